// Round 8
// baseline (414.385 us; speedup 1.0000x reference)
//
#include <hip/hip_runtime.h>

constexpr int N_NODES  = 100000;
constexpr int N_EDGES  = 1200000;
constexpr int N_GRAPHS = 1000;
constexpr int DIM      = 64;
constexpr int ODIM     = 32;
constexpr int MAXD     = 10;

constexpr int SCAN_CHUNK = 1024;
constexpr int SCAN_NB    = (N_NODES + SCAN_CHUNK - 1) / SCAN_CHUNK;  // 98

constexpr int NBKT     = 32;                        // buckets: min(deg,31)
constexpr int BPAD     = 32;                        // nodes per conv tile
constexpr int LIST_PAD = N_NODES + NBKT * (BPAD - 1);  // 100992
constexpr int N_TILES  = LIST_PAD / BPAD;           // 3156
constexpr int CONV_GRID = 2048;                     // 8 blocks/CU persistent

// ---------------- bf16 helpers (RNE pack, trivial unpack) -------------------
__device__ __forceinline__ unsigned short f2bf(float f) {
    unsigned u = __float_as_uint(f);
    u = (u + 0x7fffu + ((u >> 16) & 1u)) >> 16;
    return (unsigned short)u;
}
__device__ __forceinline__ float bflo(int u) {
    return __uint_as_float((unsigned)u << 16);
}
__device__ __forceinline__ float bfhi(int u) {
    return __uint_as_float((unsigned)u & 0xffff0000u);
}

// ---------------------------------------------------------------------------
// Fused init: deg=0, gcount=0, nodelist=-1, tile-queue counters=0
// ---------------------------------------------------------------------------
__global__ void init_kernel(int* __restrict__ deg, int* __restrict__ gcount,
                            int* __restrict__ nodelist, int* __restrict__ counters) {
    int i = blockIdx.x * 256 + threadIdx.x;
    if (i < N_NODES) deg[i] = 0;
    if (i < LIST_PAD) nodelist[i] = -1;
    if (i < NBKT) gcount[i] = 0;
    if (i < 2) counters[i] = 0;
}

// ---------------------------------------------------------------------------
// In-degree histogram
// ---------------------------------------------------------------------------
__global__ void deg_hist_kernel(const int* __restrict__ dst, int* __restrict__ deg) {
    int e = blockIdx.x * blockDim.x + threadIdx.x;
    if (e < N_EDGES) atomicAdd(&deg[dst[e]], 1);
}

// ---------------------------------------------------------------------------
// Scan phase 1 (per-block partial sums) + fused degree-bucket histogram
// ---------------------------------------------------------------------------
__global__ void scan_partial_kernel(const int* __restrict__ deg,
                                    int* __restrict__ partials,
                                    int* __restrict__ gcount) {
    __shared__ int red[256];
    __shared__ int lh[NBKT];
    int b = blockIdx.x, t = threadIdx.x;
    if (t < NBKT) lh[t] = 0;
    int base = b * SCAN_CHUNK + t * 4;
    int4 v = make_int4(0, 0, 0, 0);
    int s = 0;
    if (base < N_NODES) {
        v = *reinterpret_cast<const int4*>(deg + base);
        s = v.x + v.y + v.z + v.w;
    }
    red[t] = s;
    __syncthreads();
    for (int off = 128; off > 0; off >>= 1) {
        if (t < off) red[t] += red[t + off];
        __syncthreads();
    }
    if (base < N_NODES) {
        atomicAdd(&lh[min(v.x, NBKT - 1)], 1);
        atomicAdd(&lh[min(v.y, NBKT - 1)], 1);
        atomicAdd(&lh[min(v.z, NBKT - 1)], 1);
        atomicAdd(&lh[min(v.w, NBKT - 1)], 1);
    }
    __syncthreads();
    if (t < NBKT && lh[t]) atomicAdd(&gcount[t], lh[t]);
    if (t == 0) partials[b] = red[0];
}

// ---------------------------------------------------------------------------
// Scan phase 2 (single block): scan partials -> blockoff; heavy-first bucket
// offsets (gcur)
// ---------------------------------------------------------------------------
__global__ void scan_mid_kernel(const int* __restrict__ partials,
                                int* __restrict__ blockoff,
                                int* __restrict__ rowptr,
                                const int* __restrict__ gcount,
                                int* __restrict__ gcur) {
    __shared__ int sh[128];
    int t = threadIdx.x;
    int v = (t < SCAN_NB) ? partials[t] : 0;
    sh[t] = v;
    __syncthreads();
    for (int off = 1; off < 128; off <<= 1) {
        int u = (t >= off) ? sh[t - off] : 0;
        __syncthreads();
        sh[t] += u;
        __syncthreads();
    }
    if (t < SCAN_NB) blockoff[t] = sh[t] - v;
    if (t == SCAN_NB - 1) rowptr[N_NODES] = sh[t];
    if (t == 0) {
        // heavy-first: descending degree so long tiles are grabbed first
        int off = 0;
        for (int kk = NBKT - 1; kk >= 0; --kk) {
            gcur[kk] = off;
            off += (gcount[kk] + BPAD - 1) & ~(BPAD - 1);
        }
    }
}

// ---------------------------------------------------------------------------
// Scan phase 3: rowptr/cursor writeout + fused bucket scatter into nodelist
// ---------------------------------------------------------------------------
__global__ void scan_final_kernel(const int* __restrict__ deg,
                                  const int* __restrict__ blockoff,
                                  int* __restrict__ rowptr,
                                  int* __restrict__ cursor,
                                  int* __restrict__ gcur,
                                  int* __restrict__ nodelist) {
    __shared__ int sh[256];
    __shared__ int lh[NBKT], lbase[NBKT], lh2[NBKT];
    int b = blockIdx.x, t = threadIdx.x;
    if (t < NBKT) { lh[t] = 0; lh2[t] = 0; }
    int base = b * SCAN_CHUNK + t * 4;
    int4 v = make_int4(0, 0, 0, 0);
    if (base < N_NODES) v = *reinterpret_cast<const int4*>(deg + base);
    int s = v.x + v.y + v.z + v.w;
    sh[t] = s;
    __syncthreads();
    for (int off = 1; off < 256; off <<= 1) {
        int u = (t >= off) ? sh[t - off] : 0;
        __syncthreads();
        sh[t] += u;
        __syncthreads();
    }
    int k0 = min(v.x, NBKT - 1), k1 = min(v.y, NBKT - 1);
    int k2 = min(v.z, NBKT - 1), k3 = min(v.w, NBKT - 1);
    if (base < N_NODES) {
        int p0 = sh[t] - s + blockoff[b];
        int p1 = p0 + v.x, p2 = p1 + v.y, p3 = p2 + v.z;
        int4 pr = make_int4(p0, p1, p2, p3);
        *reinterpret_cast<int4*>(rowptr + base) = pr;
        *reinterpret_cast<int4*>(cursor + base) = pr;
        atomicAdd(&lh[k0], 1);
        atomicAdd(&lh[k1], 1);
        atomicAdd(&lh[k2], 1);
        atomicAdd(&lh[k3], 1);
    }
    __syncthreads();
    if (t < NBKT && lh[t]) lbase[t] = atomicAdd(&gcur[t], lh[t]);
    __syncthreads();
    if (base < N_NODES) {
        int r0 = atomicAdd(&lh2[k0], 1);
        nodelist[lbase[k0] + r0] = base + 0;
        int r1 = atomicAdd(&lh2[k1], 1);
        nodelist[lbase[k1] + r1] = base + 1;
        int r2 = atomicAdd(&lh2[k2], 1);
        nodelist[lbase[k2] + r2] = base + 2;
        int r3 = atomicAdd(&lh2[k3], 1);
        nodelist[lbase[k3] + r3] = base + 3;
    }
}

// ---------------------------------------------------------------------------
// Bin edges: csr[pos] = src
// ---------------------------------------------------------------------------
__global__ void fill_csr_kernel(const int* __restrict__ src, const int* __restrict__ dst,
                                int* __restrict__ cursor, int* __restrict__ csr) {
    int e = blockIdx.x * blockDim.x + threadIdx.x;
    if (e < N_EDGES) {
        int p = atomicAdd(&cursor[dst[e]], 1);
        csr[p] = src[e];
    }
}

// ---------------------------------------------------------------------------
// f32 -> bf16 row conversion
// ---------------------------------------------------------------------------
__global__ void f32_to_bf16_kernel(const float* __restrict__ in,
                                   unsigned short* __restrict__ out) {
    int i = (blockIdx.x * blockDim.x + threadIdx.x) * 4;
    if (i < N_NODES * DIM) {
        float4 v = *reinterpret_cast<const float4*>(in + i);
        ushort4 o;
        o.x = f2bf(v.x); o.y = f2bf(v.y); o.z = f2bf(v.z); o.w = f2bf(v.w);
        *reinterpret_cast<ushort4*>(out + i) = o;
    }
}

// ---------------------------------------------------------------------------
// PERSISTENT bucketed fused gather(bf16) + MFConv.
// 2048 resident blocks pull 32-node tiles from an atomic queue (perfect
// balance, full residency). Tile body identical to R6/R7.
// ---------------------------------------------------------------------------
template <int OUTMODE>
__global__ __launch_bounds__(256) void conv_bf16_kernel(
        const unsigned short* __restrict__ xbf,
        const int* __restrict__ rowptr,
        const int* __restrict__ csr,
        const int* __restrict__ nodelist,
        const float* __restrict__ Wl,
        const float* __restrict__ bl,
        const float* __restrict__ Wr,
        float* __restrict__ outf,
        unsigned short* __restrict__ outb,
        int* __restrict__ counter) {
    __shared__ float lds_h[BPAD][DIM + 4];
    __shared__ float lds_x[BPAD][DIM + 4];
    __shared__ int s_node[BPAD];
    __shared__ int s_d0;
    __shared__ int s_tile;

    int grp = threadIdx.x >> 3;
    int q   = threadIdx.x & 7;
    int mgrp = threadIdx.x >> 4;
    int mq   = threadIdx.x & 15;

    for (;;) {
        if (threadIdx.x == 0) s_tile = atomicAdd(counter, 1);
        __syncthreads();                 // s_tile visible + prev-iter LDS reads done
        int tile = s_tile;
        if (tile >= N_TILES) return;
        int base = tile * BPAD;

        int node = nodelist[base + grp];
        bool valid = (node >= 0);
        if (nodelist[base] < 0) continue;  // fully-padded tile (block-uniform)

        int beg = 0, end = 0;
        if (valid) { beg = rowptr[node]; end = rowptr[node + 1]; }

        if (threadIdx.x == 0) s_d0 = min(end - beg, MAXD);
        if (q == 0) s_node[grp] = node;

        float hs[8];
#pragma unroll
        for (int j = 0; j < 8; ++j) hs[j] = 0.f;

        int e = beg;
        for (; e + 8 <= end; e += 8) {
            int s0 = csr[e + 0], s1 = csr[e + 1], s2 = csr[e + 2], s3 = csr[e + 3];
            int s4 = csr[e + 4], s5 = csr[e + 5], s6 = csr[e + 6], s7 = csr[e + 7];
            int4 a0 = *reinterpret_cast<const int4*>(xbf + (size_t)s0 * DIM + q * 8);
            int4 a1 = *reinterpret_cast<const int4*>(xbf + (size_t)s1 * DIM + q * 8);
            int4 a2 = *reinterpret_cast<const int4*>(xbf + (size_t)s2 * DIM + q * 8);
            int4 a3 = *reinterpret_cast<const int4*>(xbf + (size_t)s3 * DIM + q * 8);
            int4 a4 = *reinterpret_cast<const int4*>(xbf + (size_t)s4 * DIM + q * 8);
            int4 a5 = *reinterpret_cast<const int4*>(xbf + (size_t)s5 * DIM + q * 8);
            int4 a6 = *reinterpret_cast<const int4*>(xbf + (size_t)s6 * DIM + q * 8);
            int4 a7 = *reinterpret_cast<const int4*>(xbf + (size_t)s7 * DIM + q * 8);
#define BFACC(a) \
            hs[0] += bflo(a.x); hs[1] += bfhi(a.x); \
            hs[2] += bflo(a.y); hs[3] += bfhi(a.y); \
            hs[4] += bflo(a.z); hs[5] += bfhi(a.z); \
            hs[6] += bflo(a.w); hs[7] += bfhi(a.w);
            BFACC(a0) BFACC(a1) BFACC(a2) BFACC(a3)
            BFACC(a4) BFACC(a5) BFACC(a6) BFACC(a7)
        }
        for (; e + 4 <= end; e += 4) {
            int s0 = csr[e + 0], s1 = csr[e + 1], s2 = csr[e + 2], s3 = csr[e + 3];
            int4 a0 = *reinterpret_cast<const int4*>(xbf + (size_t)s0 * DIM + q * 8);
            int4 a1 = *reinterpret_cast<const int4*>(xbf + (size_t)s1 * DIM + q * 8);
            int4 a2 = *reinterpret_cast<const int4*>(xbf + (size_t)s2 * DIM + q * 8);
            int4 a3 = *reinterpret_cast<const int4*>(xbf + (size_t)s3 * DIM + q * 8);
            BFACC(a0) BFACC(a1) BFACC(a2) BFACC(a3)
        }
        for (; e < end; ++e) {
            int s = csr[e];
            int4 a = *reinterpret_cast<const int4*>(xbf + (size_t)s * DIM + q * 8);
            BFACC(a)
        }
#undef BFACC

        float xv[8];
        if (valid) {
            int4 a = *reinterpret_cast<const int4*>(xbf + (size_t)node * DIM + q * 8);
            xv[0] = bflo(a.x); xv[1] = bfhi(a.x);
            xv[2] = bflo(a.y); xv[3] = bfhi(a.y);
            xv[4] = bflo(a.z); xv[5] = bfhi(a.z);
            xv[6] = bflo(a.w); xv[7] = bfhi(a.w);
        } else {
#pragma unroll
            for (int j = 0; j < 8; ++j) xv[j] = 0.f;
        }

        *reinterpret_cast<float4*>(&lds_h[grp][q * 8 + 0]) = make_float4(hs[0], hs[1], hs[2], hs[3]);
        *reinterpret_cast<float4*>(&lds_h[grp][q * 8 + 4]) = make_float4(hs[4], hs[5], hs[6], hs[7]);
        *reinterpret_cast<float4*>(&lds_x[grp][q * 8 + 0]) = make_float4(xv[0], xv[1], xv[2], xv[3]);
        *reinterpret_cast<float4*>(&lds_x[grp][q * 8 + 4]) = make_float4(xv[4], xv[5], xv[6], xv[7]);
        __syncthreads();

        int d0 = s_d0;
        const float* wl = Wl + (size_t)d0 * DIM * DIM + mq * 4;
        const float* wr = Wr + (size_t)d0 * DIM * DIM + mq * 4;
        float4 accA = *reinterpret_cast<const float4*>(bl + d0 * DIM + mq * 4);
        float4 accB = accA;

#pragma unroll 8
        for (int i = 0; i < DIM; ++i) {
            float4 wlv = *reinterpret_cast<const float4*>(wl + i * DIM);
            float4 wrv = *reinterpret_cast<const float4*>(wr + i * DIM);
            float hA = lds_h[mgrp][i],      xA = lds_x[mgrp][i];
            float hB = lds_h[mgrp + 16][i], xB = lds_x[mgrp + 16][i];
            accA.x += hA * wlv.x + xA * wrv.x;
            accA.y += hA * wlv.y + xA * wrv.y;
            accA.z += hA * wlv.z + xA * wrv.z;
            accA.w += hA * wlv.w + xA * wrv.w;
            accB.x += hB * wlv.x + xB * wrv.x;
            accB.y += hB * wlv.y + xB * wrv.y;
            accB.z += hB * wlv.z + xB * wrv.z;
            accB.w += hB * wlv.w + xB * wrv.w;
        }

        int nodeA = s_node[mgrp];
        int nodeB = s_node[mgrp + 16];
        if (OUTMODE == 0) {
            if (nodeA >= 0)
                *reinterpret_cast<float4*>(outf + (size_t)nodeA * DIM + mq * 4) = accA;
            if (nodeB >= 0)
                *reinterpret_cast<float4*>(outf + (size_t)nodeB * DIM + mq * 4) = accB;
        } else {
            if (nodeA >= 0) {
                ushort4 o;
                o.x = f2bf(fmaxf(accA.x, 0.f)); o.y = f2bf(fmaxf(accA.y, 0.f));
                o.z = f2bf(fmaxf(accA.z, 0.f)); o.w = f2bf(fmaxf(accA.w, 0.f));
                *reinterpret_cast<ushort4*>(outb + (size_t)nodeA * DIM + mq * 4) = o;
            }
            if (nodeB >= 0) {
                ushort4 o;
                o.x = f2bf(fmaxf(accB.x, 0.f)); o.y = f2bf(fmaxf(accB.y, 0.f));
                o.z = f2bf(fmaxf(accB.z, 0.f)); o.w = f2bf(fmaxf(accB.w, 0.f));
                *reinterpret_cast<ushort4*>(outb + (size_t)nodeB * DIM + mq * 4) = o;
            }
        }
        // loop-top __syncthreads() orders these LDS reads vs next tile's writes
    }
}

// ---------------------------------------------------------------------------
// Fused global_add_pool(relu(emb)) + MLP head; one block per graph.
// Graph bounds found by in-block binary search on sorted batch.
// ---------------------------------------------------------------------------
__global__ void pool_head_kernel(const float* __restrict__ emb,
                                 const int* __restrict__ batch,
                                 const float* __restrict__ W1,
                                 const float* __restrict__ b1,
                                 const float* __restrict__ W2,
                                 const float* __restrict__ b2,
                                 float* __restrict__ pred) {
    __shared__ float red[4][DIM];
    __shared__ float garr[DIM];
    __shared__ float hid[DIM];
    int gi = blockIdx.x;
    int w = threadIdx.x >> 6;
    int lane = threadIdx.x & 63;

    int lo = 0, hi = N_NODES;
    while (lo < hi) { int mid = (lo + hi) >> 1; if (batch[mid] < gi) lo = mid + 1; else hi = mid; }
    int beg = lo;
    hi = N_NODES;
    while (lo < hi) { int mid = (lo + hi) >> 1; if (batch[mid] < gi + 1) lo = mid + 1; else hi = mid; }
    int end = lo;

    float acc = 0.f;
    for (int n = beg + w; n < end; n += 4)
        acc += fmaxf(emb[(size_t)n * DIM + lane], 0.f);
    red[w][lane] = acc;
    __syncthreads();
    if (w == 0)
        garr[lane] = red[0][lane] + red[1][lane] + red[2][lane] + red[3][lane];
    __syncthreads();

    if (threadIdx.x < DIM) {
        int o = threadIdx.x;
        float a = b1[o];
#pragma unroll 8
        for (int i = 0; i < DIM; ++i) a += garr[i] * W1[i * DIM + o];
        hid[o] = a;
    }
    __syncthreads();
    if (threadIdx.x < ODIM) {
        int o = threadIdx.x;
        float p = b2[o];
#pragma unroll 8
        for (int i = 0; i < DIM; ++i) p += hid[i] * W2[i * ODIM + o];
        pred[(size_t)gi * ODIM + o] = p;
    }
}

extern "C" void kernel_launch(void* const* d_in, const int* in_sizes, int n_in,
                              void* d_out, int out_size, void* d_ws, size_t ws_size,
                              hipStream_t stream) {
    const float* x    = (const float*)d_in[0];
    const int* eidx   = (const int*)d_in[1];
    const int* src    = eidx;
    const int* dst    = eidx + N_EDGES;
    const int* batch  = (const int*)d_in[2];
    const float* Wl1  = (const float*)d_in[4];
    const float* bl1  = (const float*)d_in[5];
    const float* Wr1  = (const float*)d_in[6];
    const float* Wl2  = (const float*)d_in[7];
    const float* bl2  = (const float*)d_in[8];
    const float* Wr2  = (const float*)d_in[9];
    const float* W1   = (const float*)d_in[10];
    const float* b1   = (const float*)d_in[11];
    const float* W2   = (const float*)d_in[12];
    const float* b2   = (const float*)d_in[13];

    float* emb  = (float*)d_out;                          // [N_NODES, 64]
    float* pred = (float*)d_out + (size_t)N_NODES * DIM;  // [N_GRAPHS, 32]

    // Workspace layout (int counts all multiples of 4 -> 16B alignment kept)
    int* deg      = (int*)d_ws;                  // [100000]
    int* rowptr   = deg + N_NODES;               // [100004]
    int* cursor   = rowptr + N_NODES + 4;        // [100000]
    int* csr      = cursor + N_NODES;            // [1200000]
    int* partials = csr + N_EDGES;               // [100]
    int* blockoff = partials + 100;              // [100]
    int* gcount   = blockoff + 100;              // [32]
    int* gcur     = gcount + NBKT;               // [32]
    int* counters = gcur + NBKT;                 // [4]
    int* nodelist = counters + 4;                // [100992]
    unsigned short* xbf = (unsigned short*)(nodelist + LIST_PAD);  // [N*64] bf16
    unsigned short* hbf = xbf + (size_t)N_NODES * DIM;             // [N*64] bf16

    init_kernel<<<(LIST_PAD + 255) / 256, 256, 0, stream>>>(deg, gcount, nodelist, counters);
    deg_hist_kernel<<<(N_EDGES + 255) / 256, 256, 0, stream>>>(dst, deg);
    scan_partial_kernel<<<SCAN_NB, 256, 0, stream>>>(deg, partials, gcount);
    scan_mid_kernel<<<1, 128, 0, stream>>>(partials, blockoff, rowptr, gcount, gcur);
    scan_final_kernel<<<SCAN_NB, 256, 0, stream>>>(deg, blockoff, rowptr, cursor,
                                                   gcur, nodelist);
    fill_csr_kernel<<<(N_EDGES + 255) / 256, 256, 0, stream>>>(src, dst, cursor, csr);
    f32_to_bf16_kernel<<<(N_NODES * DIM / 4 + 255) / 256, 256, 0, stream>>>(x, xbf);

    // conv1: persistent gather + matvec + relu -> hbf
    conv_bf16_kernel<1><<<CONV_GRID, 256, 0, stream>>>(xbf, rowptr, csr, nodelist,
                                                       Wl1, bl1, Wr1, nullptr, hbf,
                                                       counters + 0);
    // conv2: persistent gather + matvec -> emb (f32, pre-activation output)
    conv_bf16_kernel<0><<<CONV_GRID, 256, 0, stream>>>(hbf, rowptr, csr, nodelist,
                                                       Wl2, bl2, Wr2, emb, nullptr,
                                                       counters + 1);
    // fused pool + head
    pool_head_kernel<<<N_GRAPHS, 256, 0, stream>>>(emb, batch, W1, b1, W2, b2, pred);
}

// Round 9
// 403.873 us; speedup vs baseline: 1.0260x; 1.0260x over previous
//
#include <hip/hip_runtime.h>

constexpr int N_NODES  = 100000;
constexpr int N_EDGES  = 1200000;
constexpr int N_GRAPHS = 1000;
constexpr int DIM      = 64;
constexpr int ODIM     = 32;
constexpr int MAXD     = 10;

constexpr int NR    = 4;          // src ranges (3.2MB bf16 window each, fits 4MB XCD L2)
constexpr int RDIV  = 25000;      // src / RDIV -> range id
constexpr int NBINS = N_NODES * NR;   // 400000

constexpr int SCAN_CHUNK = 1024;
constexpr int SCAN_NB    = (NBINS + SCAN_CHUNK - 1) / SCAN_CHUNK;  // 391

constexpr int NBKT     = 32;
constexpr int BPAD     = 32;
constexpr int LIST_PAD = N_NODES + NBKT * (BPAD - 1);  // 100992
constexpr int MV_BLK   = LIST_PAD / BPAD;              // 3156
constexpr int GATH_BLK = N_NODES / 32;                 // 3125

// ---------------- bf16 helpers -------------------
__device__ __forceinline__ unsigned short f2bf(float f) {
    unsigned u = __float_as_uint(f);
    u = (u + 0x7fffu + ((u >> 16) & 1u)) >> 16;
    return (unsigned short)u;
}
__device__ __forceinline__ float bflo(int u) {
    return __uint_as_float((unsigned)u << 16);
}
__device__ __forceinline__ float bfhi(int u) {
    return __uint_as_float((unsigned)u & 0xffff0000u);
}
__device__ __forceinline__ int packbf2(float lo, float hi) {
    return (int)f2bf(lo) | ((int)f2bf(hi) << 16);
}

// ---------------------------------------------------------------------------
// Init: cnt2 = 0, nodelist = -1, gcount = 0
// ---------------------------------------------------------------------------
__global__ void init_kernel(int* __restrict__ cnt2, int* __restrict__ gcount,
                            int* __restrict__ nodelist) {
    int i = blockIdx.x * 256 + threadIdx.x;
    if (i < NBINS) cnt2[i] = 0;
    if (i < LIST_PAD) nodelist[i] = -1;
    if (i < NBKT) gcount[i] = 0;
}

// ---------------------------------------------------------------------------
// Bin histogram over (dst, src-range): cnt2[4*dst + src/RDIV]++
// ---------------------------------------------------------------------------
__global__ void bin_hist_kernel(const int* __restrict__ src, const int* __restrict__ dst,
                                int* __restrict__ cnt2) {
    int e = blockIdx.x * blockDim.x + threadIdx.x;
    if (e < N_EDGES) {
        int key = dst[e] * NR + src[e] / RDIV;
        atomicAdd(&cnt2[key], 1);
    }
}

// ---------------------------------------------------------------------------
// Scan phase 1 over cnt2 (400K): per-block partials + bucket histogram.
// Each int4 (4-aligned) = one node's 4 range-counts -> total degree.
// ---------------------------------------------------------------------------
__global__ void scan_partial_kernel(const int* __restrict__ cnt2,
                                    int* __restrict__ partials,
                                    int* __restrict__ gcount) {
    __shared__ int red[256];
    __shared__ int lh[NBKT];
    int b = blockIdx.x, t = threadIdx.x;
    if (t < NBKT) lh[t] = 0;
    int base = b * SCAN_CHUNK + t * 4;
    int s = 0;
    if (base < NBINS) {
        int4 v = *reinterpret_cast<const int4*>(cnt2 + base);
        s = v.x + v.y + v.z + v.w;
    }
    red[t] = s;
    __syncthreads();
    for (int off = 128; off > 0; off >>= 1) {
        if (t < off) red[t] += red[t + off];
        __syncthreads();
    }
    if (base < NBINS) atomicAdd(&lh[min(s, NBKT - 1)], 1);
    __syncthreads();
    if (t < NBKT && lh[t]) atomicAdd(&gcount[t], lh[t]);
    if (t == 0) partials[b] = red[0];
}

// ---------------------------------------------------------------------------
// Scan phase 2 (single 512-thr block): scan 391 partials; bucket offsets
// (ascending, BPAD-padded); rowptr2[NBINS] = E
// ---------------------------------------------------------------------------
__global__ void scan_mid_kernel(const int* __restrict__ partials,
                                int* __restrict__ blockoff,
                                int* __restrict__ rowptr2,
                                const int* __restrict__ gcount,
                                int* __restrict__ gcur) {
    __shared__ int sh[512];
    int t = threadIdx.x;
    int v = (t < SCAN_NB) ? partials[t] : 0;
    sh[t] = v;
    __syncthreads();
    for (int off = 1; off < 512; off <<= 1) {
        int u = (t >= off) ? sh[t - off] : 0;
        __syncthreads();
        sh[t] += u;
        __syncthreads();
    }
    if (t < SCAN_NB) blockoff[t] = sh[t] - v;
    if (t == 0) {
        rowptr2[NBINS] = N_EDGES;
        int off = 0;
        for (int k = 0; k < NBKT; ++k) {
            gcur[k] = off;
            off += (gcount[k] + BPAD - 1) & ~(BPAD - 1);
        }
    }
}

// ---------------------------------------------------------------------------
// Scan phase 3: rowptr2/cursor2 writeout + bucket scatter (one node per thread)
// ---------------------------------------------------------------------------
__global__ void scan_final_kernel(const int* __restrict__ cnt2,
                                  const int* __restrict__ blockoff,
                                  int* __restrict__ rowptr2,
                                  int* __restrict__ cursor2,
                                  int* __restrict__ gcur,
                                  int* __restrict__ nodelist) {
    __shared__ int sh[256];
    __shared__ int lh[NBKT], lbase[NBKT], lh2[NBKT];
    int b = blockIdx.x, t = threadIdx.x;
    if (t < NBKT) { lh[t] = 0; lh2[t] = 0; }
    int base = b * SCAN_CHUNK + t * 4;
    int4 v = make_int4(0, 0, 0, 0);
    if (base < NBINS) v = *reinterpret_cast<const int4*>(cnt2 + base);
    int s = v.x + v.y + v.z + v.w;
    sh[t] = s;
    __syncthreads();
    for (int off = 1; off < 256; off <<= 1) {
        int u = (t >= off) ? sh[t - off] : 0;
        __syncthreads();
        sh[t] += u;
        __syncthreads();
    }
    int k = min(s, NBKT - 1);
    if (base < NBINS) {
        int p0 = sh[t] - s + blockoff[b];
        int p1 = p0 + v.x, p2 = p1 + v.y, p3 = p2 + v.z;
        int4 pr = make_int4(p0, p1, p2, p3);
        *reinterpret_cast<int4*>(rowptr2 + base) = pr;
        *reinterpret_cast<int4*>(cursor2 + base) = pr;
        atomicAdd(&lh[k], 1);
    }
    __syncthreads();
    if (t < NBKT && lh[t]) lbase[t] = atomicAdd(&gcur[t], lh[t]);
    __syncthreads();
    if (base < NBINS) {
        int r = atomicAdd(&lh2[k], 1);
        nodelist[lbase[k] + r] = base >> 2;   // node id
    }
}

// ---------------------------------------------------------------------------
// Bin edges: csr[pos] = src (within its (dst,range) bin)
// ---------------------------------------------------------------------------
__global__ void fill_csr_kernel(const int* __restrict__ src, const int* __restrict__ dst,
                                int* __restrict__ cursor2, int* __restrict__ csr) {
    int e = blockIdx.x * blockDim.x + threadIdx.x;
    if (e < N_EDGES) {
        int s = src[e];
        int key = dst[e] * NR + s / RDIV;
        int p = atomicAdd(&cursor2[key], 1);
        csr[p] = s;
    }
}

// ---------------------------------------------------------------------------
// f32 -> bf16 row conversion
// ---------------------------------------------------------------------------
__global__ void f32_to_bf16_kernel(const float* __restrict__ in,
                                   unsigned short* __restrict__ out) {
    int i = (blockIdx.x * blockDim.x + threadIdx.x) * 4;
    if (i < N_NODES * DIM) {
        float4 v = *reinterpret_cast<const float4*>(in + i);
        ushort4 o;
        o.x = f2bf(v.x); o.y = f2bf(v.y); o.z = f2bf(v.z); o.w = f2bf(v.w);
        *reinterpret_cast<ushort4*>(out + i) = o;
    }
}

// ---------------------------------------------------------------------------
// Phase gather: all nodes, edges with src in range r only (3.2MB L2 window).
// 8 lanes/node, 32 nodes/block, node-linear order (sequential partial RMW).
// hpart[node][dim] bf16 accumulates across the NR dispatches.
// ---------------------------------------------------------------------------
__global__ __launch_bounds__(256) void conv_gather_kernel(
        const unsigned short* __restrict__ xtab,
        const int* __restrict__ rowptr2,
        const int* __restrict__ csr,
        unsigned short* __restrict__ hpart,
        int r, int first) {
    int node = blockIdx.x * 32 + (threadIdx.x >> 3);
    int q = threadIdx.x & 7;
    int j = node * NR + r;
    int beg = rowptr2[j];
    int end = rowptr2[j + 1];

    float hs[8];
#pragma unroll
    for (int i = 0; i < 8; ++i) hs[i] = 0.f;

#define BFACC(a) \
    hs[0] += bflo(a.x); hs[1] += bfhi(a.x); \
    hs[2] += bflo(a.y); hs[3] += bfhi(a.y); \
    hs[4] += bflo(a.z); hs[5] += bfhi(a.z); \
    hs[6] += bflo(a.w); hs[7] += bfhi(a.w);

    int e = beg;
    for (; e + 4 <= end; e += 4) {
        int s0 = csr[e + 0], s1 = csr[e + 1], s2 = csr[e + 2], s3 = csr[e + 3];
        int4 a0 = *reinterpret_cast<const int4*>(xtab + (size_t)s0 * DIM + q * 8);
        int4 a1 = *reinterpret_cast<const int4*>(xtab + (size_t)s1 * DIM + q * 8);
        int4 a2 = *reinterpret_cast<const int4*>(xtab + (size_t)s2 * DIM + q * 8);
        int4 a3 = *reinterpret_cast<const int4*>(xtab + (size_t)s3 * DIM + q * 8);
        BFACC(a0) BFACC(a1) BFACC(a2) BFACC(a3)
    }
    for (; e < end; ++e) {
        int s = csr[e];
        int4 a = *reinterpret_cast<const int4*>(xtab + (size_t)s * DIM + q * 8);
        BFACC(a)
    }

    size_t off = (size_t)node * DIM + q * 8;
    if (!first) {
        int4 old = *reinterpret_cast<const int4*>(hpart + off);
        BFACC(old)
    }
#undef BFACC
    int4 o;
    o.x = packbf2(hs[0], hs[1]);
    o.y = packbf2(hs[2], hs[3]);
    o.z = packbf2(hs[4], hs[5]);
    o.w = packbf2(hs[6], hs[7]);
    *reinterpret_cast<int4*>(hpart + off) = o;
}

// ---------------------------------------------------------------------------
// Bucketed matvec: 32 nodes/block (uniform weight index), R6-proven structure.
// Reads hpart (bf16 neighbor sum) + xtab (bf16 self row).
// OUTMODE 0: f32 -> outf.  OUTMODE 1: relu + bf16 -> outb.
// ---------------------------------------------------------------------------
template <int OUTMODE>
__global__ __launch_bounds__(256) void conv_mv_kernel(
        const unsigned short* __restrict__ xtab,
        const unsigned short* __restrict__ hpart,
        const int* __restrict__ rowptr2,
        const int* __restrict__ nodelist,
        const float* __restrict__ Wl,
        const float* __restrict__ bl,
        const float* __restrict__ Wr,
        float* __restrict__ outf,
        unsigned short* __restrict__ outb) {
    __shared__ float lds_h[BPAD][DIM + 4];
    __shared__ float lds_x[BPAD][DIM + 4];
    __shared__ int s_node[BPAD];
    __shared__ int s_d0;

    int base = blockIdx.x * BPAD;
    int node0 = nodelist[base];
    if (node0 < 0) return;

    int grp = threadIdx.x >> 3;
    int q   = threadIdx.x & 7;
    int node = nodelist[base + grp];
    bool valid = (node >= 0);

    if (threadIdx.x == 0)
        s_d0 = min(rowptr2[node0 * NR + NR] - rowptr2[node0 * NR], MAXD);
    if (q == 0) s_node[grp] = node;

    float hv[8], xv[8];
    if (valid) {
        int4 a = *reinterpret_cast<const int4*>(hpart + (size_t)node * DIM + q * 8);
        hv[0] = bflo(a.x); hv[1] = bfhi(a.x);
        hv[2] = bflo(a.y); hv[3] = bfhi(a.y);
        hv[4] = bflo(a.z); hv[5] = bfhi(a.z);
        hv[6] = bflo(a.w); hv[7] = bfhi(a.w);
        int4 b = *reinterpret_cast<const int4*>(xtab + (size_t)node * DIM + q * 8);
        xv[0] = bflo(b.x); xv[1] = bfhi(b.x);
        xv[2] = bflo(b.y); xv[3] = bfhi(b.y);
        xv[4] = bflo(b.z); xv[5] = bfhi(b.z);
        xv[6] = bflo(b.w); xv[7] = bfhi(b.w);
    } else {
#pragma unroll
        for (int i = 0; i < 8; ++i) { hv[i] = 0.f; xv[i] = 0.f; }
    }

    *reinterpret_cast<float4*>(&lds_h[grp][q * 8 + 0]) = make_float4(hv[0], hv[1], hv[2], hv[3]);
    *reinterpret_cast<float4*>(&lds_h[grp][q * 8 + 4]) = make_float4(hv[4], hv[5], hv[6], hv[7]);
    *reinterpret_cast<float4*>(&lds_x[grp][q * 8 + 0]) = make_float4(xv[0], xv[1], xv[2], xv[3]);
    *reinterpret_cast<float4*>(&lds_x[grp][q * 8 + 4]) = make_float4(xv[4], xv[5], xv[6], xv[7]);
    __syncthreads();

    int mgrp = threadIdx.x >> 4;
    int mq   = threadIdx.x & 15;
    int d0 = s_d0;
    const float* wl = Wl + (size_t)d0 * DIM * DIM + mq * 4;
    const float* wr = Wr + (size_t)d0 * DIM * DIM + mq * 4;
    float4 accA = *reinterpret_cast<const float4*>(bl + d0 * DIM + mq * 4);
    float4 accB = accA;

#pragma unroll 8
    for (int i = 0; i < DIM; ++i) {
        float4 wlv = *reinterpret_cast<const float4*>(wl + i * DIM);
        float4 wrv = *reinterpret_cast<const float4*>(wr + i * DIM);
        float hA = lds_h[mgrp][i],      xA = lds_x[mgrp][i];
        float hB = lds_h[mgrp + 16][i], xB = lds_x[mgrp + 16][i];
        accA.x += hA * wlv.x + xA * wrv.x;
        accA.y += hA * wlv.y + xA * wrv.y;
        accA.z += hA * wlv.z + xA * wrv.z;
        accA.w += hA * wlv.w + xA * wrv.w;
        accB.x += hB * wlv.x + xB * wrv.x;
        accB.y += hB * wlv.y + xB * wrv.y;
        accB.z += hB * wlv.z + xB * wrv.z;
        accB.w += hB * wlv.w + xB * wrv.w;
    }

    int nodeA = s_node[mgrp];
    int nodeB = s_node[mgrp + 16];
    if (OUTMODE == 0) {
        if (nodeA >= 0)
            *reinterpret_cast<float4*>(outf + (size_t)nodeA * DIM + mq * 4) = accA;
        if (nodeB >= 0)
            *reinterpret_cast<float4*>(outf + (size_t)nodeB * DIM + mq * 4) = accB;
    } else {
        if (nodeA >= 0) {
            ushort4 o;
            o.x = f2bf(fmaxf(accA.x, 0.f)); o.y = f2bf(fmaxf(accA.y, 0.f));
            o.z = f2bf(fmaxf(accA.z, 0.f)); o.w = f2bf(fmaxf(accA.w, 0.f));
            *reinterpret_cast<ushort4*>(outb + (size_t)nodeA * DIM + mq * 4) = o;
        }
        if (nodeB >= 0) {
            ushort4 o;
            o.x = f2bf(fmaxf(accB.x, 0.f)); o.y = f2bf(fmaxf(accB.y, 0.f));
            o.z = f2bf(fmaxf(accB.z, 0.f)); o.w = f2bf(fmaxf(accB.w, 0.f));
            *reinterpret_cast<ushort4*>(outb + (size_t)nodeB * DIM + mq * 4) = o;
        }
    }
}

// ---------------------------------------------------------------------------
// Fused global_add_pool(relu(emb)) + MLP head; one block per graph.
// ---------------------------------------------------------------------------
__global__ void pool_head_kernel(const float* __restrict__ emb,
                                 const int* __restrict__ batch,
                                 const float* __restrict__ W1,
                                 const float* __restrict__ b1,
                                 const float* __restrict__ W2,
                                 const float* __restrict__ b2,
                                 float* __restrict__ pred) {
    __shared__ float red[4][DIM];
    __shared__ float garr[DIM];
    __shared__ float hid[DIM];
    int gi = blockIdx.x;
    int w = threadIdx.x >> 6;
    int lane = threadIdx.x & 63;

    int lo = 0, hi = N_NODES;
    while (lo < hi) { int mid = (lo + hi) >> 1; if (batch[mid] < gi) lo = mid + 1; else hi = mid; }
    int beg = lo;
    hi = N_NODES;
    while (lo < hi) { int mid = (lo + hi) >> 1; if (batch[mid] < gi + 1) lo = mid + 1; else hi = mid; }
    int end = lo;

    float acc = 0.f;
    for (int n = beg + w; n < end; n += 4)
        acc += fmaxf(emb[(size_t)n * DIM + lane], 0.f);
    red[w][lane] = acc;
    __syncthreads();
    if (w == 0)
        garr[lane] = red[0][lane] + red[1][lane] + red[2][lane] + red[3][lane];
    __syncthreads();

    if (threadIdx.x < DIM) {
        int o = threadIdx.x;
        float a = b1[o];
#pragma unroll 8
        for (int i = 0; i < DIM; ++i) a += garr[i] * W1[i * DIM + o];
        hid[o] = a;
    }
    __syncthreads();
    if (threadIdx.x < ODIM) {
        int o = threadIdx.x;
        float p = b2[o];
#pragma unroll 8
        for (int i = 0; i < DIM; ++i) p += hid[i] * W2[i * ODIM + o];
        pred[(size_t)gi * ODIM + o] = p;
    }
}

extern "C" void kernel_launch(void* const* d_in, const int* in_sizes, int n_in,
                              void* d_out, int out_size, void* d_ws, size_t ws_size,
                              hipStream_t stream) {
    const float* x    = (const float*)d_in[0];
    const int* eidx   = (const int*)d_in[1];
    const int* src    = eidx;
    const int* dst    = eidx + N_EDGES;
    const int* batch  = (const int*)d_in[2];
    const float* Wl1  = (const float*)d_in[4];
    const float* bl1  = (const float*)d_in[5];
    const float* Wr1  = (const float*)d_in[6];
    const float* Wl2  = (const float*)d_in[7];
    const float* bl2  = (const float*)d_in[8];
    const float* Wr2  = (const float*)d_in[9];
    const float* W1   = (const float*)d_in[10];
    const float* b1   = (const float*)d_in[11];
    const float* W2   = (const float*)d_in[12];
    const float* b2   = (const float*)d_in[13];

    float* emb  = (float*)d_out;                          // [N_NODES, 64]
    float* pred = (float*)d_out + (size_t)N_NODES * DIM;  // [N_GRAPHS, 32]

    // Workspace (int region sizes all multiples of 4 -> 16B alignment kept)
    int* cnt2     = (int*)d_ws;                  // [400000]
    int* rowptr2  = cnt2 + NBINS;                // [400004]
    int* cursor2  = rowptr2 + NBINS + 4;         // [400000]
    int* csr      = cursor2 + NBINS;             // [1200000]
    int* partials = csr + N_EDGES;               // [400]
    int* blockoff = partials + 400;              // [400]
    int* gcount   = blockoff + 400;              // [32]
    int* gcur     = gcount + NBKT;               // [32]
    int* nodelist = gcur + NBKT;                 // [100992]
    unsigned short* xbf   = (unsigned short*)(nodelist + LIST_PAD);  // [N*64]
    unsigned short* hbf   = xbf + (size_t)N_NODES * DIM;             // [N*64]
    unsigned short* hpart = hbf + (size_t)N_NODES * DIM;             // [N*64]

    init_kernel<<<(NBINS + 255) / 256, 256, 0, stream>>>(cnt2, gcount, nodelist);
    bin_hist_kernel<<<(N_EDGES + 255) / 256, 256, 0, stream>>>(src, dst, cnt2);
    scan_partial_kernel<<<SCAN_NB, 256, 0, stream>>>(cnt2, partials, gcount);
    scan_mid_kernel<<<1, 512, 0, stream>>>(partials, blockoff, rowptr2, gcount, gcur);
    scan_final_kernel<<<SCAN_NB, 256, 0, stream>>>(cnt2, blockoff, rowptr2, cursor2,
                                                   gcur, nodelist);
    fill_csr_kernel<<<(N_EDGES + 255) / 256, 256, 0, stream>>>(src, dst, cursor2, csr);
    f32_to_bf16_kernel<<<(N_NODES * DIM / 4 + 255) / 256, 256, 0, stream>>>(x, xbf);

    // conv1: 4 L2-windowed gather phases -> hpart, then bucketed matvec -> hbf
    for (int r = 0; r < NR; ++r)
        conv_gather_kernel<<<GATH_BLK, 256, 0, stream>>>(xbf, rowptr2, csr, hpart,
                                                         r, r == 0);
    conv_mv_kernel<1><<<MV_BLK, 256, 0, stream>>>(xbf, hpart, rowptr2, nodelist,
                                                  Wl1, bl1, Wr1, nullptr, hbf);
    // conv2: same over hbf -> emb
    for (int r = 0; r < NR; ++r)
        conv_gather_kernel<<<GATH_BLK, 256, 0, stream>>>(hbf, rowptr2, csr, hpart,
                                                         r, r == 0);
    conv_mv_kernel<0><<<MV_BLK, 256, 0, stream>>>(hbf, hpart, rowptr2, nodelist,
                                                  Wl2, bl2, Wr2, emb, nullptr);
    // fused pool + head
    pool_head_kernel<<<N_GRAPHS, 256, 0, stream>>>(emb, batch, W1, b1, W2, b2, pred);
}